// Round 4
// baseline (978.687 us; speedup 1.0000x reference)
//
#include <hip/hip_runtime.h>
#include <cstddef>

#define HH 256
#define WW 256
#define NB 4
#define NFC 64
#define EMBC 512

typedef short s16x8 __attribute__((ext_vector_type(8)));
typedef float f32x4 __attribute__((ext_vector_type(4)));

static __device__ __forceinline__ unsigned short f2b(float f) {
    unsigned int u = __float_as_uint(f);
    u += 0x7FFFu + ((u >> 16) & 1u);
    return (unsigned short)(u >> 16);
}

// ---------------------------------------------------------------------------
// Modulated weights -> bf16 [b][tap][co][ci]. Block (co,b), 64 thr (ci).
// ---------------------------------------------------------------------------
__global__ void modw_kernel(const float* __restrict__ emb, const float* __restrict__ mw,
                            const float* __restrict__ mb, const float* __restrict__ bw,
                            unsigned short* __restrict__ outw)
{
    const int co = blockIdx.x, b = blockIdx.y;
    const int ci = threadIdx.x;

    const float* e = emb + (size_t)b * EMBC;
    const float* m = mw + (size_t)ci * EMBC;
    float s = mb[ci];
    for (int k = 0; k < EMBC; k += 4) {
        float4 ev = *(const float4*)(e + k);
        float4 mv = *(const float4*)(m + k);
        s += ev.x * mv.x + ev.y * mv.y + ev.z * mv.z + ev.w * mv.w;
    }

    float w[9];
    float ss = 0.f;
    const float* src = bw + ((size_t)co * NFC + ci) * 9;
#pragma unroll
    for (int k = 0; k < 9; ++k) {
        float v = (1.0f / 24.0f) * src[k] * s;
        w[k] = v;
        ss += v * v;
    }
#pragma unroll
    for (int off = 32; off; off >>= 1) ss += __shfl_xor(ss, off);
    float demod = rsqrtf(ss + 1e-8f);

#pragma unroll
    for (int k = 0; k < 9; ++k)
        outw[(((size_t)b * 9 + k) * NFC + co) * NFC + ci] = f2b(w[k] * demod);
}

// ---------------------------------------------------------------------------
// Fixed-weight transform: w[co][ci][3][3] f32 -> wt[tap][COP][64] bf16
// ---------------------------------------------------------------------------
__global__ void fixw_kernel(const float* __restrict__ w, unsigned short* __restrict__ wt,
                            int Cout, int COP)
{
    int idx = blockIdx.x * 256 + threadIdx.x;
    int total = 9 * COP * NFC;
    if (idx >= total) return;
    int k = idx / (COP * NFC);
    int rem = idx - k * (COP * NFC);
    int co = rem / NFC, ci = rem - co * NFC;
    float v = (co < Cout) ? w[((size_t)co * NFC + ci) * 9 + k] : 0.f;
    wt[idx] = f2b(v);
}

// ---------------------------------------------------------------------------
// conv_first weights: [64][3][3][3] f32 -> [64][32] bf16 (k = ci*9+kh*3+kw, pad)
// ---------------------------------------------------------------------------
__global__ void firstw_kernel(const float* __restrict__ w, unsigned short* __restrict__ wt)
{
    int idx = blockIdx.x * 256 + threadIdx.x;   // 64*32
    if (idx >= 64 * 32) return;
    int co = idx >> 5, k = idx & 31;
    wt[idx] = (k < 27) ? f2b(w[co * 27 + k]) : 0;
}

// ---------------------------------------------------------------------------
// im2col for layer 0: fp32 NCHW x -> bf16 [px][32], k = ci*9+kh*3+kw (27 real)
// ---------------------------------------------------------------------------
__global__ __launch_bounds__(256) void im2col_kernel(
    const float* __restrict__ x, unsigned short* __restrict__ ib)
{
    const int p = blockIdx.x * 256 + threadIdx.x;          // 0 .. 4*256*256-1
    const int b = p >> 16, hw = p & 0xFFFF;
    const int h = hw >> 8, w = hw & 255;

    unsigned short kv[32];
#pragma unroll
    for (int ci = 0; ci < 3; ++ci)
#pragma unroll
        for (int kh = 0; kh < 3; ++kh)
#pragma unroll
            for (int kw = 0; kw < 3; ++kw) {
                int gh = h + kh - 1, gw = w + kw - 1;
                float v = 0.f;
                if ((unsigned)gh < HH && (unsigned)gw < WW)
                    v = x[(((size_t)b * 3 + ci) * HH + gh) * WW + gw];
                kv[ci * 9 + kh * 3 + kw] = f2b(v);
            }
#pragma unroll
    for (int k = 27; k < 32; ++k) kv[k] = 0;

    unsigned short* op = ib + (size_t)p * 32;
#pragma unroll
    for (int q = 0; q < 4; ++q)
        *(uint4*)(op + q * 8) = *(const uint4*)(kv + q * 8);
}

// ---------------------------------------------------------------------------
// Layer 0 GEMM: [px][32] x [64][32] -> bf16 NHWC, bias+lrelu. K=32 single step.
// ---------------------------------------------------------------------------
__global__ __launch_bounds__(256) void conv_first_mm(
    const unsigned short* __restrict__ ib, const unsigned short* __restrict__ wt,
    const float* __restrict__ bias, unsigned short* __restrict__ out)
{
    const int lane = threadIdx.x & 63, wid = threadIdx.x >> 6;
    const int m16 = lane & 15, kg = lane >> 4;

    s16x8 a[4];
    float4 bv[4];
#pragma unroll
    for (int mf = 0; mf < 4; ++mf) {
        a[mf] = *(const s16x8*)(wt + (mf * 16 + m16) * 32 + kg * 8);
        bv[mf] = *(const float4*)(bias + mf * 16 + kg * 4);
    }

    const int t0 = blockIdx.x * 16 + wid * 4;
#pragma unroll
    for (int t = 0; t < 4; ++t) {
        const size_t px0 = (size_t)(t0 + t) * 16;
        s16x8 bfr = *(const s16x8*)(ib + (px0 + m16) * 32 + kg * 8);
#pragma unroll
        for (int mf = 0; mf < 4; ++mf) {
            f32x4 c = (f32x4)(0.f);
            c = __builtin_amdgcn_mfma_f32_16x16x32_bf16(a[mf], bfr, c, 0, 0, 0);
            unsigned short pk[4];
#pragma unroll
            for (int e = 0; e < 4; ++e) {
                float v = c[e] + (&bv[mf].x)[e];
                v = v >= 0.f ? v : 0.1f * v;
                pk[e] = f2b(v);
            }
            *(ushort4*)(out + (px0 + m16) * NFC + mf * 16 + kg * 4) = *(ushort4*)pk;
        }
    }
}

// ---------------------------------------------------------------------------
// Main MFMA conv. A-frag pipeline: 4 buffers, prefetch distance 3 -> target
// buffer (g+3)&3 never aliases current g&3 (fixes round-3 WAR bug).
// ---------------------------------------------------------------------------
template <int MFRAGS, bool PERB, bool BIAS, bool LRELU, bool NOISE, bool OUTF32>
__global__ __launch_bounds__(256, 3) void mconv(
    const unsigned short* __restrict__ in, const unsigned short* __restrict__ wt,
    const float* __restrict__ bias, const float* __restrict__ noise,
    const float* __restrict__ wnp, void* __restrict__ outv)
{
    constexpr int COP = MFRAGS * 16;
    __shared__ uint4 xs[18 * 18 * 8];   // 41472 B

    const int tid = threadIdx.x;
    const int b = blockIdx.z, h0 = blockIdx.y * 16, w0 = blockIdx.x * 16;
    const int lane = tid & 63, wid = tid >> 6;
    const int m16 = lane & 15, kg = lane >> 4;

    const unsigned short* wbase = PERB ? wt + (size_t)b * 9 * COP * NFC : wt;
    const unsigned short* wlane = wbase + m16 * NFC + kg * 8;

    // A-frag loader: group g -> tap g>>1, half g&1
    auto LOADA = [&](int g, s16x8* a) {
        const unsigned short* p = wlane + (size_t)(g >> 1) * (COP * NFC) + (g & 1) * 32;
#pragma unroll
        for (int mf = 0; mf < MFRAGS; ++mf)
            a[mf] = *(const s16x8*)(p + mf * 16 * NFC);
    };

    s16x8 abuf[4][MFRAGS];
    LOADA(0, abuf[0]); LOADA(1, abuf[1]); LOADA(2, abuf[2]);  // in flight during staging

    // --- stage halo tile (zero-padded) with slot swizzle ---
    for (int idx = tid; idx < 18 * 18 * 8; idx += 256) {
        int row = idx / 144, rem = idx - row * 144;
        int w = rem >> 3, slot = rem & 7;
        int gh = h0 + row - 1, gw = w0 + w - 1;
        uint4 v = make_uint4(0, 0, 0, 0);
        if ((unsigned)gh < HH && (unsigned)gw < WW)
            v = *(const uint4*)(in + (((size_t)b * HH + gh) * WW + gw) * NFC + slot * 8);
        xs[(row * 18 + w) * 8 + (slot ^ (w & 7))] = v;
    }
    __syncthreads();

    f32x4 acc[MFRAGS][4];
#pragma unroll
    for (int mf = 0; mf < MFRAGS; ++mf)
#pragma unroll
        for (int r = 0; r < 4; ++r) acc[mf][r] = (f32x4)(0.f);

#pragma unroll
    for (int g = 0; g < 18; ++g) {
        const int tap = g >> 1, half = g & 1;
        const int kh = tap / 3, kw = tap - kh * 3;
        const int lw = m16 + kw;
        const int slot = (half * 4 + kg) ^ (lw & 7);

        if (g + 3 < 18) LOADA(g + 3, abuf[(g + 3) & 3]);  // distinct buffer, ~3 groups ahead

        s16x8 bf[4];
#pragma unroll
        for (int r = 0; r < 4; ++r) {
            const int lrow = wid * 4 + r + kh;
            bf[r] = *(const s16x8*)&xs[(lrow * 18 + lw) * 8 + slot];
        }
#pragma unroll
        for (int r = 0; r < 4; ++r)
#pragma unroll
            for (int mf = 0; mf < MFRAGS; ++mf)
                acc[mf][r] = __builtin_amdgcn_mfma_f32_16x16x32_bf16(
                    abuf[g & 3][mf], bf[r], acc[mf][r], 0, 0, 0);
    }

    // --- epilogue ---
    const int wcol = w0 + m16;
    const float wn = NOISE ? wnp[0] : 0.f;
#pragma unroll
    for (int r = 0; r < 4; ++r) {
        const int h = h0 + wid * 4 + r;
        float nz = 0.f;
        if (NOISE) nz = noise[((size_t)b * HH + h) * WW + wcol];
#pragma unroll
        for (int mf = 0; mf < MFRAGS; ++mf) {
            const int cob = mf * 16 + kg * 4;
            f32x4 v = acc[mf][r];
            float4 bvv = make_float4(0.f, 0.f, 0.f, 0.f);
            if (BIAS) bvv = *(const float4*)(bias + cob);
            float o[4];
#pragma unroll
            for (int e = 0; e < 4; ++e) {
                float t = v[e] + (BIAS ? (&bvv.x)[e] : 0.f);
                if (NOISE) t += wn * nz;
                if (LRELU) t = t >= 0.f ? t : 0.1f * t;
                o[e] = t;
            }
            if (OUTF32) {
                float* of = (float*)outv;
#pragma unroll
                for (int e = 0; e < 4; ++e) {
                    int co = cob + e;
                    if (co < 3)
                        of[(((size_t)b * 3 + co) * HH + h) * WW + wcol] = o[e];
                }
            } else {
                unsigned short pk[4];
#pragma unroll
                for (int e = 0; e < 4; ++e) pk[e] = f2b(o[e]);
                unsigned short* ob = (unsigned short*)outv;
                *(ushort4*)(ob + (((size_t)b * HH + h) * WW + wcol) * NFC + cob) = *(ushort4*)pk;
            }
        }
    }
}

// ---------------------------------------------------------------------------
extern "C" void kernel_launch(void* const* d_in, const int* in_sizes, int n_in,
                              void* d_out, int out_size, void* d_ws, size_t ws_size,
                              hipStream_t stream)
{
    auto F = [&](int i) { return (const float*)d_in[i]; };
    const float* x       = F(0);
    const float* emb     = F(1);
    const float* noise[3] = {F(2), F(3), F(4)};
    const float* w_first = F(5);  const float* b_first = F(6);
    const float* w_hr[5] = {F(7), F(9), F(11), F(13), F(15)};
    const float* b_hr[5] = {F(8), F(10), F(12), F(14), F(16)};
    const float* w_last  = F(17); const float* b_last = F(18);
    const float *m_mw[3], *m_mb[3], *m_w[3], *m_cw[3], *m_cb[3], *m_wn[3];
    for (int i = 0; i < 3; ++i) {
        int o = 19 + 6 * i;
        m_mw[i] = F(o); m_mb[i] = F(o + 1); m_w[i] = F(o + 2);
        m_cw[i] = F(o + 3); m_cb[i] = F(o + 4); m_wn[i] = F(o + 5);
    }

    // workspace layout (bf16 = unsigned short)
    const size_t ACT = (size_t)NB * HH * WW * NFC;
    const size_t NPX = (size_t)NB * HH * WW;
    unsigned short* act0 = (unsigned short*)d_ws;
    unsigned short* act1 = act0 + ACT;
    unsigned short* p = act1 + ACT;
    unsigned short* wmod[3];
    for (int i = 0; i < 3; ++i) { wmod[i] = p; p += (size_t)NB * 9 * NFC * NFC; }
    unsigned short* wfix[8];
    for (int i = 0; i < 8; ++i) { wfix[i] = p; p += (size_t)9 * NFC * NFC; }
    unsigned short* wlast = p;  p += 9 * 16 * NFC;
    unsigned short* wfirst = p; p += 64 * 32;
    unsigned short* ib = p;     // [NPX][32]

    // --- weight prep + im2col ---
    dim3 mg(NFC, NB);
    for (int i = 0; i < 3; ++i)
        modw_kernel<<<mg, NFC, 0, stream>>>(emb, m_mw[i], m_mb[i], m_w[i], wmod[i]);
    for (int i = 0; i < 3; ++i)
        fixw_kernel<<<(9 * 64 * 64 + 255) / 256, 256, 0, stream>>>(m_cw[i], wfix[i], 64, 64);
    for (int i = 0; i < 5; ++i)
        fixw_kernel<<<(9 * 64 * 64 + 255) / 256, 256, 0, stream>>>(w_hr[i], wfix[3 + i], 64, 64);
    fixw_kernel<<<(9 * 16 * 64 + 255) / 256, 256, 0, stream>>>(w_last, wlast, 3, 16);
    firstw_kernel<<<8, 256, 0, stream>>>(w_first, wfirst);
    im2col_kernel<<<NPX / 256, 256, 0, stream>>>(x, ib);

    // layer 0
    conv_first_mm<<<1024, 256, 0, stream>>>(ib, wfirst, b_first, act0);

    dim3 grid(WW / 16, HH / 16, NB), blk(256);
    unsigned short* cur = act0;
    unsigned short* nxt = act1;
    auto swap = [&]() { unsigned short* t = cur; cur = nxt; nxt = t; };

    for (int i = 0; i < 3; ++i) {
        mconv<4, true, false, false, true, false>
            <<<grid, blk, 0, stream>>>(cur, wmod[i], nullptr, noise[i], m_wn[i], nxt);
        swap();
        mconv<4, false, true, true, false, false>
            <<<grid, blk, 0, stream>>>(cur, wfix[i], m_cb[i], nullptr, nullptr, nxt);
        swap();
        mconv<4, false, true, false, false, false>
            <<<grid, blk, 0, stream>>>(cur, wfix[3 + i], b_hr[i], nullptr, nullptr, nxt);
        swap();
    }
    mconv<4, false, true, false, false, false>
        <<<grid, blk, 0, stream>>>(cur, wfix[6], b_hr[3], nullptr, nullptr, nxt);
    swap();
    mconv<4, false, true, false, false, false>
        <<<grid, blk, 0, stream>>>(cur, wfix[7], b_hr[4], nullptr, nullptr, nxt);
    swap();
    mconv<1, false, true, false, false, true>
        <<<grid, blk, 0, stream>>>(cur, wlast, b_last, nullptr, nullptr, d_out);
}

// Round 5
// 946.633 us; speedup vs baseline: 1.0339x; 1.0339x over previous
//
#include <hip/hip_runtime.h>
#include <cstddef>

#define HH 256
#define WW 256
#define NB 4
#define NFC 64
#define EMBC 512

typedef short s16x8 __attribute__((ext_vector_type(8)));
typedef float f32x4 __attribute__((ext_vector_type(4)));

static __device__ __forceinline__ unsigned short f2b(float f) {
    unsigned int u = __float_as_uint(f);
    u += 0x7FFFu + ((u >> 16) & 1u);
    return (unsigned short)(u >> 16);
}

// ---------------------------------------------------------------------------
// Modulated weights -> bf16 [b][tap][co][ci]. Block (co,b), 64 thr (ci).
// ---------------------------------------------------------------------------
__global__ void modw_kernel(const float* __restrict__ emb, const float* __restrict__ mw,
                            const float* __restrict__ mb, const float* __restrict__ bw,
                            unsigned short* __restrict__ outw)
{
    const int co = blockIdx.x, b = blockIdx.y;
    const int ci = threadIdx.x;

    const float* e = emb + (size_t)b * EMBC;
    const float* m = mw + (size_t)ci * EMBC;
    float s = mb[ci];
    for (int k = 0; k < EMBC; k += 4) {
        float4 ev = *(const float4*)(e + k);
        float4 mv = *(const float4*)(m + k);
        s += ev.x * mv.x + ev.y * mv.y + ev.z * mv.z + ev.w * mv.w;
    }

    float w[9];
    float ss = 0.f;
    const float* src = bw + ((size_t)co * NFC + ci) * 9;
#pragma unroll
    for (int k = 0; k < 9; ++k) {
        float v = (1.0f / 24.0f) * src[k] * s;
        w[k] = v;
        ss += v * v;
    }
#pragma unroll
    for (int off = 32; off; off >>= 1) ss += __shfl_xor(ss, off);
    float demod = rsqrtf(ss + 1e-8f);

#pragma unroll
    for (int k = 0; k < 9; ++k)
        outw[(((size_t)b * 9 + k) * NFC + co) * NFC + ci] = f2b(w[k] * demod);
}

// ---------------------------------------------------------------------------
// Fixed-weight transform: w[co][ci][3][3] f32 -> wt[tap][COP][64] bf16
// ---------------------------------------------------------------------------
__global__ void fixw_kernel(const float* __restrict__ w, unsigned short* __restrict__ wt,
                            int Cout, int COP)
{
    int idx = blockIdx.x * 256 + threadIdx.x;
    int total = 9 * COP * NFC;
    if (idx >= total) return;
    int k = idx / (COP * NFC);
    int rem = idx - k * (COP * NFC);
    int co = rem / NFC, ci = rem - co * NFC;
    float v = (co < Cout) ? w[((size_t)co * NFC + ci) * 9 + k] : 0.f;
    wt[idx] = f2b(v);
}

// ---------------------------------------------------------------------------
// conv_first weights: [64][3][3][3] f32 -> [64][32] bf16 (k = ci*9+kh*3+kw, pad)
// ---------------------------------------------------------------------------
__global__ void firstw_kernel(const float* __restrict__ w, unsigned short* __restrict__ wt)
{
    int idx = blockIdx.x * 256 + threadIdx.x;   // 64*32
    if (idx >= 64 * 32) return;
    int co = idx >> 5, k = idx & 31;
    wt[idx] = (k < 27) ? f2b(w[co * 27 + k]) : 0;
}

// ---------------------------------------------------------------------------
// im2col for layer 0: fp32 NCHW x -> bf16 [px][32], k = ci*9+kh*3+kw (27 real)
// ---------------------------------------------------------------------------
__global__ __launch_bounds__(256) void im2col_kernel(
    const float* __restrict__ x, unsigned short* __restrict__ ib)
{
    const int p = blockIdx.x * 256 + threadIdx.x;          // 0 .. 4*256*256-1
    const int b = p >> 16, hw = p & 0xFFFF;
    const int h = hw >> 8, w = hw & 255;

    unsigned short kv[32];
#pragma unroll
    for (int ci = 0; ci < 3; ++ci)
#pragma unroll
        for (int kh = 0; kh < 3; ++kh)
#pragma unroll
            for (int kw = 0; kw < 3; ++kw) {
                int gh = h + kh - 1, gw = w + kw - 1;
                float v = 0.f;
                if ((unsigned)gh < HH && (unsigned)gw < WW)
                    v = x[(((size_t)b * 3 + ci) * HH + gh) * WW + gw];
                kv[ci * 9 + kh * 3 + kw] = f2b(v);
            }
#pragma unroll
    for (int k = 27; k < 32; ++k) kv[k] = 0;

    unsigned short* op = ib + (size_t)p * 32;
#pragma unroll
    for (int q = 0; q < 4; ++q)
        *(uint4*)(op + q * 8) = *(const uint4*)(kv + q * 8);
}

// ---------------------------------------------------------------------------
// Layer 0 GEMM: [px][32] x [64][32] -> bf16 NHWC, bias+lrelu. K=32 single step.
// ---------------------------------------------------------------------------
__global__ __launch_bounds__(256) void conv_first_mm(
    const unsigned short* __restrict__ ib, const unsigned short* __restrict__ wt,
    const float* __restrict__ bias, unsigned short* __restrict__ out)
{
    const int lane = threadIdx.x & 63, wid = threadIdx.x >> 6;
    const int m16 = lane & 15, kg = lane >> 4;

    s16x8 a[4];
    float4 bv[4];
#pragma unroll
    for (int mf = 0; mf < 4; ++mf) {
        a[mf] = *(const s16x8*)(wt + (mf * 16 + m16) * 32 + kg * 8);
        bv[mf] = *(const float4*)(bias + mf * 16 + kg * 4);
    }

    const int t0 = blockIdx.x * 16 + wid * 4;
#pragma unroll
    for (int t = 0; t < 4; ++t) {
        const size_t px0 = (size_t)(t0 + t) * 16;
        s16x8 bfr = *(const s16x8*)(ib + (px0 + m16) * 32 + kg * 8);
#pragma unroll
        for (int mf = 0; mf < 4; ++mf) {
            f32x4 c = (f32x4)(0.f);
            c = __builtin_amdgcn_mfma_f32_16x16x32_bf16(a[mf], bfr, c, 0, 0, 0);
            unsigned short pk[4];
#pragma unroll
            for (int e = 0; e < 4; ++e) {
                float v = c[e] + (&bv[mf].x)[e];
                v = v >= 0.f ? v : 0.1f * v;
                pk[e] = f2b(v);
            }
            *(ushort4*)(out + (px0 + m16) * NFC + mf * 16 + kg * 4) = *(ushort4*)pk;
        }
    }
}

// ---------------------------------------------------------------------------
// Main MFMA conv. 1D grid (1024) with bijective XCD swizzle.
// Staging: two-phase (all global loads -> regs, then all ds_writes) so 11
// loads/thread stay in flight (round-4 was 1-deep: 2.7 TB/s TCC ceiling).
// A-frag pipeline: 4 buffers, prefetch distance 3.
// ---------------------------------------------------------------------------
template <int MFRAGS, bool PERB, bool BIAS, bool LRELU, bool NOISE, bool OUTF32>
__global__ __launch_bounds__(256, 3) void mconv(
    const unsigned short* __restrict__ in, const unsigned short* __restrict__ wt,
    const float* __restrict__ bias, const float* __restrict__ noise,
    const float* __restrict__ wnp, void* __restrict__ outv)
{
    constexpr int COP = MFRAGS * 16;
    __shared__ uint4 xs[18 * 18 * 8];   // 41472 B

    const int tid = threadIdx.x;
    // XCD-aware swizzle: 1024 blocks, 8 XCDs -> contiguous 128-block chunks
    const int flat = blockIdx.x;
    const int swz = (flat & 7) * 128 + (flat >> 3);
    const int b = swz >> 8, remb = swz & 255;
    const int h0 = (remb >> 4) * 16, w0 = (remb & 15) * 16;

    const int lane = tid & 63, wid = tid >> 6;
    const int m16 = lane & 15, kg = lane >> 4;

    const unsigned short* wbase = PERB ? wt + (size_t)b * 9 * COP * NFC : wt;
    const unsigned short* wlane = wbase + m16 * NFC + kg * 8;

    // A-frag loader: group g -> tap g>>1, half g&1
    auto LOADA = [&](int g, s16x8* a) {
        const unsigned short* p = wlane + (size_t)(g >> 1) * (COP * NFC) + (g & 1) * 32;
#pragma unroll
        for (int mf = 0; mf < MFRAGS; ++mf)
            a[mf] = *(const s16x8*)(p + mf * 16 * NFC);
    };

    s16x8 abuf[4][MFRAGS];
    LOADA(0, abuf[0]); LOADA(1, abuf[1]); LOADA(2, abuf[2]);  // in flight during staging

    // --- phase 1: issue ALL staging loads (11 independent per thread) ---
    uint4 u[11];
#pragma unroll
    for (int i = 0; i < 11; ++i) {
        const int idx = tid + i * 256;
        u[i] = make_uint4(0, 0, 0, 0);
        if (idx < 2592) {
            const int row = idx / 144, rem2 = idx - row * 144;
            const int w = rem2 >> 3, slot = rem2 & 7;
            const int gh = h0 + row - 1, gw = w0 + w - 1;
            if ((unsigned)gh < HH && (unsigned)gw < WW)
                u[i] = *(const uint4*)(in + (((size_t)b * HH + gh) * WW + gw) * NFC + slot * 8);
        }
    }
    // --- phase 2: ds_write all (compiler emits counted vmcnt waits) ---
#pragma unroll
    for (int i = 0; i < 11; ++i) {
        const int idx = tid + i * 256;
        if (idx < 2592) {
            const int row = idx / 144, rem2 = idx - row * 144;
            const int w = rem2 >> 3, slot = rem2 & 7;
            xs[(row * 18 + w) * 8 + (slot ^ (w & 7))] = u[i];
        }
    }
    __syncthreads();

    f32x4 acc[MFRAGS][4];
#pragma unroll
    for (int mf = 0; mf < MFRAGS; ++mf)
#pragma unroll
        for (int r = 0; r < 4; ++r) acc[mf][r] = (f32x4)(0.f);

#pragma unroll
    for (int g = 0; g < 18; ++g) {
        const int tap = g >> 1, half = g & 1;
        const int kh = tap / 3, kw = tap - kh * 3;
        const int lw = m16 + kw;
        const int slot = (half * 4 + kg) ^ (lw & 7);

        if (g + 3 < 18) LOADA(g + 3, abuf[(g + 3) & 3]);  // distinct buffer, ~3 groups ahead

        s16x8 bf[4];
#pragma unroll
        for (int r = 0; r < 4; ++r) {
            const int lrow = wid * 4 + r + kh;
            bf[r] = *(const s16x8*)&xs[(lrow * 18 + lw) * 8 + slot];
        }
#pragma unroll
        for (int r = 0; r < 4; ++r)
#pragma unroll
            for (int mf = 0; mf < MFRAGS; ++mf)
                acc[mf][r] = __builtin_amdgcn_mfma_f32_16x16x32_bf16(
                    abuf[g & 3][mf], bf[r], acc[mf][r], 0, 0, 0);
    }

    // --- epilogue ---
    const int wcol = w0 + m16;
    const float wn = NOISE ? wnp[0] : 0.f;
#pragma unroll
    for (int r = 0; r < 4; ++r) {
        const int h = h0 + wid * 4 + r;
        float nz = 0.f;
        if (NOISE) nz = noise[((size_t)b * HH + h) * WW + wcol];
#pragma unroll
        for (int mf = 0; mf < MFRAGS; ++mf) {
            const int cob = mf * 16 + kg * 4;
            f32x4 v = acc[mf][r];
            float4 bvv = make_float4(0.f, 0.f, 0.f, 0.f);
            if (BIAS) bvv = *(const float4*)(bias + cob);
            float o[4];
#pragma unroll
            for (int e = 0; e < 4; ++e) {
                float t = v[e] + (BIAS ? (&bvv.x)[e] : 0.f);
                if (NOISE) t += wn * nz;
                if (LRELU) t = t >= 0.f ? t : 0.1f * t;
                o[e] = t;
            }
            if (OUTF32) {
                float* of = (float*)outv;
#pragma unroll
                for (int e = 0; e < 4; ++e) {
                    int co = cob + e;
                    if (co < 3)
                        of[(((size_t)b * 3 + co) * HH + h) * WW + wcol] = o[e];
                }
            } else {
                unsigned short pk[4];
#pragma unroll
                for (int e = 0; e < 4; ++e) pk[e] = f2b(o[e]);
                unsigned short* ob = (unsigned short*)outv;
                *(ushort4*)(ob + (((size_t)b * HH + h) * WW + wcol) * NFC + cob) = *(ushort4*)pk;
            }
        }
    }
}

// ---------------------------------------------------------------------------
extern "C" void kernel_launch(void* const* d_in, const int* in_sizes, int n_in,
                              void* d_out, int out_size, void* d_ws, size_t ws_size,
                              hipStream_t stream)
{
    auto F = [&](int i) { return (const float*)d_in[i]; };
    const float* x       = F(0);
    const float* emb     = F(1);
    const float* noise[3] = {F(2), F(3), F(4)};
    const float* w_first = F(5);  const float* b_first = F(6);
    const float* w_hr[5] = {F(7), F(9), F(11), F(13), F(15)};
    const float* b_hr[5] = {F(8), F(10), F(12), F(14), F(16)};
    const float* w_last  = F(17); const float* b_last = F(18);
    const float *m_mw[3], *m_mb[3], *m_w[3], *m_cw[3], *m_cb[3], *m_wn[3];
    for (int i = 0; i < 3; ++i) {
        int o = 19 + 6 * i;
        m_mw[i] = F(o); m_mb[i] = F(o + 1); m_w[i] = F(o + 2);
        m_cw[i] = F(o + 3); m_cb[i] = F(o + 4); m_wn[i] = F(o + 5);
    }

    // workspace layout (bf16 = unsigned short)
    const size_t ACT = (size_t)NB * HH * WW * NFC;
    const size_t NPX = (size_t)NB * HH * WW;
    unsigned short* act0 = (unsigned short*)d_ws;
    unsigned short* act1 = act0 + ACT;
    unsigned short* p = act1 + ACT;
    unsigned short* wmod[3];
    for (int i = 0; i < 3; ++i) { wmod[i] = p; p += (size_t)NB * 9 * NFC * NFC; }
    unsigned short* wfix[8];
    for (int i = 0; i < 8; ++i) { wfix[i] = p; p += (size_t)9 * NFC * NFC; }
    unsigned short* wlast = p;  p += 9 * 16 * NFC;
    unsigned short* wfirst = p; p += 64 * 32;
    unsigned short* ib = p;     // [NPX][32]

    // --- weight prep + im2col ---
    dim3 mg(NFC, NB);
    for (int i = 0; i < 3; ++i)
        modw_kernel<<<mg, NFC, 0, stream>>>(emb, m_mw[i], m_mb[i], m_w[i], wmod[i]);
    for (int i = 0; i < 3; ++i)
        fixw_kernel<<<(9 * 64 * 64 + 255) / 256, 256, 0, stream>>>(m_cw[i], wfix[i], 64, 64);
    for (int i = 0; i < 5; ++i)
        fixw_kernel<<<(9 * 64 * 64 + 255) / 256, 256, 0, stream>>>(w_hr[i], wfix[3 + i], 64, 64);
    fixw_kernel<<<(9 * 16 * 64 + 255) / 256, 256, 0, stream>>>(w_last, wlast, 3, 16);
    firstw_kernel<<<8, 256, 0, stream>>>(w_first, wfirst);
    im2col_kernel<<<NPX / 256, 256, 0, stream>>>(x, ib);

    // layer 0
    conv_first_mm<<<1024, 256, 0, stream>>>(ib, wfirst, b_first, act0);

    const int grid = 1024;   // flattened; mconv swizzles internally
    unsigned short* cur = act0;
    unsigned short* nxt = act1;
    auto swap = [&]() { unsigned short* t = cur; cur = nxt; nxt = t; };

    for (int i = 0; i < 3; ++i) {
        mconv<4, true, false, false, true, false>
            <<<grid, 256, 0, stream>>>(cur, wmod[i], nullptr, noise[i], m_wn[i], nxt);
        swap();
        mconv<4, false, true, true, false, false>
            <<<grid, 256, 0, stream>>>(cur, wfix[i], m_cb[i], nullptr, nullptr, nxt);
        swap();
        mconv<4, false, true, false, false, false>
            <<<grid, 256, 0, stream>>>(cur, wfix[3 + i], b_hr[i], nullptr, nullptr, nxt);
        swap();
    }
    mconv<4, false, true, false, false, false>
        <<<grid, 256, 0, stream>>>(cur, wfix[6], b_hr[3], nullptr, nullptr, nxt);
    swap();
    mconv<4, false, true, false, false, false>
        <<<grid, 256, 0, stream>>>(cur, wfix[7], b_hr[4], nullptr, nullptr, nxt);
    swap();
    mconv<1, false, true, false, false, true>
        <<<grid, 256, 0, stream>>>(cur, wlast, b_last, nullptr, nullptr, d_out);
}

// Round 6
// 856.727 us; speedup vs baseline: 1.1424x; 1.1049x over previous
//
#include <hip/hip_runtime.h>
#include <cstddef>

#define HH 256
#define WW 256
#define NB 4
#define NFC 64
#define EMBC 512

typedef short s16x8 __attribute__((ext_vector_type(8)));
typedef float f32x4 __attribute__((ext_vector_type(4)));

static __device__ __forceinline__ unsigned short f2b(float f) {
    unsigned int u = __float_as_uint(f);
    u += 0x7FFFu + ((u >> 16) & 1u);
    return (unsigned short)(u >> 16);
}

// ---------------------------------------------------------------------------
// Modulated weights -> bf16 [b][tap][co][ci]. Block (co,b), 64 thr (ci).
// ---------------------------------------------------------------------------
__global__ void modw_kernel(const float* __restrict__ emb, const float* __restrict__ mw,
                            const float* __restrict__ mb, const float* __restrict__ bw,
                            unsigned short* __restrict__ outw)
{
    const int co = blockIdx.x, b = blockIdx.y;
    const int ci = threadIdx.x;

    const float* e = emb + (size_t)b * EMBC;
    const float* m = mw + (size_t)ci * EMBC;
    float s = mb[ci];
    for (int k = 0; k < EMBC; k += 4) {
        float4 ev = *(const float4*)(e + k);
        float4 mv = *(const float4*)(m + k);
        s += ev.x * mv.x + ev.y * mv.y + ev.z * mv.z + ev.w * mv.w;
    }

    float w[9];
    float ss = 0.f;
    const float* src = bw + ((size_t)co * NFC + ci) * 9;
#pragma unroll
    for (int k = 0; k < 9; ++k) {
        float v = (1.0f / 24.0f) * src[k] * s;
        w[k] = v;
        ss += v * v;
    }
#pragma unroll
    for (int off = 32; off; off >>= 1) ss += __shfl_xor(ss, off);
    float demod = rsqrtf(ss + 1e-8f);

#pragma unroll
    for (int k = 0; k < 9; ++k)
        outw[(((size_t)b * 9 + k) * NFC + co) * NFC + ci] = f2b(w[k] * demod);
}

// ---------------------------------------------------------------------------
// Fixed-weight transform: w[co][ci][3][3] f32 -> wt[tap][COP][64] bf16
// ---------------------------------------------------------------------------
__global__ void fixw_kernel(const float* __restrict__ w, unsigned short* __restrict__ wt,
                            int Cout, int COP)
{
    int idx = blockIdx.x * 256 + threadIdx.x;
    int total = 9 * COP * NFC;
    if (idx >= total) return;
    int k = idx / (COP * NFC);
    int rem = idx - k * (COP * NFC);
    int co = rem / NFC, ci = rem - co * NFC;
    float v = (co < Cout) ? w[((size_t)co * NFC + ci) * 9 + k] : 0.f;
    wt[idx] = f2b(v);
}

// ---------------------------------------------------------------------------
// conv_first weights: [64][3][3][3] f32 -> [64][32] bf16 (k = ci*9+kh*3+kw, pad)
// ---------------------------------------------------------------------------
__global__ void firstw_kernel(const float* __restrict__ w, unsigned short* __restrict__ wt)
{
    int idx = blockIdx.x * 256 + threadIdx.x;   // 64*32
    if (idx >= 64 * 32) return;
    int co = idx >> 5, k = idx & 31;
    wt[idx] = (k < 27) ? f2b(w[co * 27 + k]) : 0;
}

// ---------------------------------------------------------------------------
// im2col for layer 0: fp32 NCHW x -> bf16 [px][32], k = ci*9+kh*3+kw (27 real)
// ---------------------------------------------------------------------------
__global__ __launch_bounds__(256) void im2col_kernel(
    const float* __restrict__ x, unsigned short* __restrict__ ib)
{
    const int p = blockIdx.x * 256 + threadIdx.x;          // 0 .. 4*256*256-1
    const int b = p >> 16, hw = p & 0xFFFF;
    const int h = hw >> 8, w = hw & 255;

    unsigned short kv[32];
#pragma unroll
    for (int ci = 0; ci < 3; ++ci)
#pragma unroll
        for (int kh = 0; kh < 3; ++kh)
#pragma unroll
            for (int kw = 0; kw < 3; ++kw) {
                int gh = h + kh - 1, gw = w + kw - 1;
                float v = 0.f;
                if ((unsigned)gh < HH && (unsigned)gw < WW)
                    v = x[(((size_t)b * 3 + ci) * HH + gh) * WW + gw];
                kv[ci * 9 + kh * 3 + kw] = f2b(v);
            }
#pragma unroll
    for (int k = 27; k < 32; ++k) kv[k] = 0;

    unsigned short* op = ib + (size_t)p * 32;
#pragma unroll
    for (int q = 0; q < 4; ++q)
        *(uint4*)(op + q * 8) = *(const uint4*)(kv + q * 8);
}

// ---------------------------------------------------------------------------
// Layer 0 GEMM: [px][32] x [64][32] -> bf16 NHWC, bias+lrelu. K=32 single step.
// Epilogue: per-wave LDS transpose -> full-line contiguous stores.
// ---------------------------------------------------------------------------
__global__ __launch_bounds__(256) void conv_first_mm(
    const unsigned short* __restrict__ ib, const unsigned short* __restrict__ wt,
    const float* __restrict__ bias, unsigned short* __restrict__ out)
{
    __shared__ unsigned short tb[4][16][72];   // per-wave transpose buffer (pad 144B)
    const int lane = threadIdx.x & 63, wid = threadIdx.x >> 6;
    const int m16 = lane & 15, kg = lane >> 4;

    s16x8 a[4];
    float4 bv[4];
#pragma unroll
    for (int mf = 0; mf < 4; ++mf) {
        a[mf] = *(const s16x8*)(wt + (mf * 16 + m16) * 32 + kg * 8);
        bv[mf] = *(const float4*)(bias + mf * 16 + kg * 4);
    }

    const int t0 = blockIdx.x * 16 + wid * 4;
#pragma unroll
    for (int t = 0; t < 4; ++t) {
        const size_t px0 = (size_t)(t0 + t) * 16;
        s16x8 bfr = *(const s16x8*)(ib + (px0 + m16) * 32 + kg * 8);
#pragma unroll
        for (int mf = 0; mf < 4; ++mf) {
            f32x4 c = (f32x4)(0.f);
            c = __builtin_amdgcn_mfma_f32_16x16x32_bf16(a[mf], bfr, c, 0, 0, 0);
            unsigned short pk[4];
#pragma unroll
            for (int e = 0; e < 4; ++e) {
                float v = c[e] + (&bv[mf].x)[e];
                v = v >= 0.f ? v : 0.1f * v;
                pk[e] = f2b(v);
            }
            *(uint2*)&tb[wid][m16][mf * 16 + kg * 4] = *(uint2*)pk;
        }
        asm volatile("s_waitcnt lgkmcnt(0)" ::: "memory");
#pragma unroll
        for (int s = 0; s < 2; ++s) {
            const int p = s * 8 + (lane >> 3);
            uint4 rd = *(const uint4*)&tb[wid][p][(lane & 7) * 8];
            *(uint4*)(out + (px0 + p) * NFC + (lane & 7) * 8) = rd;
        }
    }
}

// ---------------------------------------------------------------------------
// Main MFMA conv. 1D grid (1024) with XCD swizzle; two-phase staging;
// A-frag pipeline (4 buffers, distance 3); full-line C-stores via per-wave
// LDS transpose (round-6 fix for 4.8x write amplification).
// ---------------------------------------------------------------------------
template <int MFRAGS, bool PERB, bool BIAS, bool LRELU, bool NOISE, bool OUTF32>
__global__ __launch_bounds__(256, 3) void mconv(
    const unsigned short* __restrict__ in, const unsigned short* __restrict__ wt,
    const float* __restrict__ bias, const float* __restrict__ noise,
    const float* __restrict__ wnp, void* __restrict__ outv)
{
    constexpr int COP = MFRAGS * 16;
    __shared__ uint4 xs[18 * 18 * 8];            // 41472 B
    __shared__ unsigned short tb[4][16][72];     // 9216 B, per-wave C transpose

    const int tid = threadIdx.x;
    // XCD-aware swizzle: 1024 blocks, 8 XCDs -> contiguous 128-block chunks
    const int flat = blockIdx.x;
    const int swz = (flat & 7) * 128 + (flat >> 3);
    const int b = swz >> 8, remb = swz & 255;
    const int h0 = (remb >> 4) * 16, w0 = (remb & 15) * 16;

    const int lane = tid & 63, wid = tid >> 6;
    const int m16 = lane & 15, kg = lane >> 4;

    const unsigned short* wbase = PERB ? wt + (size_t)b * 9 * COP * NFC : wt;
    const unsigned short* wlane = wbase + m16 * NFC + kg * 8;

    auto LOADA = [&](int g, s16x8* a) {
        const unsigned short* p = wlane + (size_t)(g >> 1) * (COP * NFC) + (g & 1) * 32;
#pragma unroll
        for (int mf = 0; mf < MFRAGS; ++mf)
            a[mf] = *(const s16x8*)(p + mf * 16 * NFC);
    };

    s16x8 abuf[4][MFRAGS];
    LOADA(0, abuf[0]); LOADA(1, abuf[1]); LOADA(2, abuf[2]);

    // --- phase 1: issue ALL staging loads (11 independent per thread) ---
    uint4 u[11];
#pragma unroll
    for (int i = 0; i < 11; ++i) {
        const int idx = tid + i * 256;
        u[i] = make_uint4(0, 0, 0, 0);
        if (idx < 2592) {
            const int row = idx / 144, rem2 = idx - row * 144;
            const int w = rem2 >> 3, slot = rem2 & 7;
            const int gh = h0 + row - 1, gw = w0 + w - 1;
            if ((unsigned)gh < HH && (unsigned)gw < WW)
                u[i] = *(const uint4*)(in + (((size_t)b * HH + gh) * WW + gw) * NFC + slot * 8);
        }
    }
    // --- phase 2: ds_write all ---
#pragma unroll
    for (int i = 0; i < 11; ++i) {
        const int idx = tid + i * 256;
        if (idx < 2592) {
            const int row = idx / 144, rem2 = idx - row * 144;
            const int w = rem2 >> 3, slot = rem2 & 7;
            xs[(row * 18 + w) * 8 + (slot ^ (w & 7))] = u[i];
        }
    }
    __syncthreads();

    f32x4 acc[MFRAGS][4];
#pragma unroll
    for (int mf = 0; mf < MFRAGS; ++mf)
#pragma unroll
        for (int r = 0; r < 4; ++r) acc[mf][r] = (f32x4)(0.f);

#pragma unroll
    for (int g = 0; g < 18; ++g) {
        const int tap = g >> 1, half = g & 1;
        const int kh = tap / 3, kw = tap - kh * 3;
        const int lw = m16 + kw;
        const int slot = (half * 4 + kg) ^ (lw & 7);

        if (g + 3 < 18) LOADA(g + 3, abuf[(g + 3) & 3]);

        s16x8 bf[4];
#pragma unroll
        for (int r = 0; r < 4; ++r) {
            const int lrow = wid * 4 + r + kh;
            bf[r] = *(const s16x8*)&xs[(lrow * 18 + lw) * 8 + slot];
        }
#pragma unroll
        for (int r = 0; r < 4; ++r)
#pragma unroll
            for (int mf = 0; mf < MFRAGS; ++mf)
                acc[mf][r] = __builtin_amdgcn_mfma_f32_16x16x32_bf16(
                    abuf[g & 3][mf], bf[r], acc[mf][r], 0, 0, 0);
    }

    // --- epilogue ---
    const float wn = NOISE ? wnp[0] : 0.f;
#pragma unroll
    for (int r = 0; r < 4; ++r) {
        const int h = h0 + wid * 4 + r;
        float nz = 0.f;
        if (NOISE) nz = noise[((size_t)b * HH + h) * WW + w0 + m16];

        if (!OUTF32) {
            // pack into per-wave LDS transpose buffer
#pragma unroll
            for (int mf = 0; mf < MFRAGS; ++mf) {
                const int cob = mf * 16 + kg * 4;
                f32x4 v = acc[mf][r];
                float4 bvv = make_float4(0.f, 0.f, 0.f, 0.f);
                if (BIAS) bvv = *(const float4*)(bias + cob);
                unsigned short pk[4];
#pragma unroll
                for (int e = 0; e < 4; ++e) {
                    float t = v[e] + (BIAS ? (&bvv.x)[e] : 0.f);
                    if (NOISE) t += wn * nz;
                    if (LRELU) t = t >= 0.f ? t : 0.1f * t;
                    pk[e] = f2b(t);
                }
                *(uint2*)&tb[wid][m16][cob] = *(uint2*)pk;
            }
            asm volatile("s_waitcnt lgkmcnt(0)" ::: "memory");
            // read back contiguous 16B/lane -> fully contiguous 1KB/wave store
            unsigned short* ob = (unsigned short*)outv;
#pragma unroll
            for (int s = 0; s < 2; ++s) {
                const int p = s * 8 + (lane >> 3);
                uint4 rd = *(const uint4*)&tb[wid][p][(lane & 7) * 8];
                *(uint4*)(ob + (((size_t)b * HH + h) * WW + w0 + p) * NFC + (lane & 7) * 8) = rd;
            }
        } else {
#pragma unroll
            for (int mf = 0; mf < MFRAGS; ++mf) {
                const int cob = mf * 16 + kg * 4;
                f32x4 v = acc[mf][r];
                float4 bvv = make_float4(0.f, 0.f, 0.f, 0.f);
                if (BIAS) bvv = *(const float4*)(bias + cob);
                float* of = (float*)outv;
#pragma unroll
                for (int e = 0; e < 4; ++e) {
                    float t = v[e] + (BIAS ? (&bvv.x)[e] : 0.f);
                    if (NOISE) t += wn * nz;
                    if (LRELU) t = t >= 0.f ? t : 0.1f * t;
                    int co = cob + e;
                    if (co < 3)
                        of[(((size_t)b * 3 + co) * HH + h) * WW + w0 + m16] = t;
                }
            }
        }
    }
}

// ---------------------------------------------------------------------------
extern "C" void kernel_launch(void* const* d_in, const int* in_sizes, int n_in,
                              void* d_out, int out_size, void* d_ws, size_t ws_size,
                              hipStream_t stream)
{
    auto F = [&](int i) { return (const float*)d_in[i]; };
    const float* x       = F(0);
    const float* emb     = F(1);
    const float* noise[3] = {F(2), F(3), F(4)};
    const float* w_first = F(5);  const float* b_first = F(6);
    const float* w_hr[5] = {F(7), F(9), F(11), F(13), F(15)};
    const float* b_hr[5] = {F(8), F(10), F(12), F(14), F(16)};
    const float* w_last  = F(17); const float* b_last = F(18);
    const float *m_mw[3], *m_mb[3], *m_w[3], *m_cw[3], *m_cb[3], *m_wn[3];
    for (int i = 0; i < 3; ++i) {
        int o = 19 + 6 * i;
        m_mw[i] = F(o); m_mb[i] = F(o + 1); m_w[i] = F(o + 2);
        m_cw[i] = F(o + 3); m_cb[i] = F(o + 4); m_wn[i] = F(o + 5);
    }

    // workspace layout (bf16 = unsigned short)
    const size_t ACT = (size_t)NB * HH * WW * NFC;
    const size_t NPX = (size_t)NB * HH * WW;
    unsigned short* act0 = (unsigned short*)d_ws;
    unsigned short* act1 = act0 + ACT;
    unsigned short* p = act1 + ACT;
    unsigned short* wmod[3];
    for (int i = 0; i < 3; ++i) { wmod[i] = p; p += (size_t)NB * 9 * NFC * NFC; }
    unsigned short* wfix[8];
    for (int i = 0; i < 8; ++i) { wfix[i] = p; p += (size_t)9 * NFC * NFC; }
    unsigned short* wlast = p;  p += 9 * 16 * NFC;
    unsigned short* wfirst = p; p += 64 * 32;
    unsigned short* ib = p;     // [NPX][32]

    // --- weight prep + im2col ---
    dim3 mg(NFC, NB);
    for (int i = 0; i < 3; ++i)
        modw_kernel<<<mg, NFC, 0, stream>>>(emb, m_mw[i], m_mb[i], m_w[i], wmod[i]);
    for (int i = 0; i < 3; ++i)
        fixw_kernel<<<(9 * 64 * 64 + 255) / 256, 256, 0, stream>>>(m_cw[i], wfix[i], 64, 64);
    for (int i = 0; i < 5; ++i)
        fixw_kernel<<<(9 * 64 * 64 + 255) / 256, 256, 0, stream>>>(w_hr[i], wfix[3 + i], 64, 64);
    fixw_kernel<<<(9 * 16 * 64 + 255) / 256, 256, 0, stream>>>(w_last, wlast, 3, 16);
    firstw_kernel<<<8, 256, 0, stream>>>(w_first, wfirst);
    im2col_kernel<<<NPX / 256, 256, 0, stream>>>(x, ib);

    // layer 0
    conv_first_mm<<<1024, 256, 0, stream>>>(ib, wfirst, b_first, act0);

    const int grid = 1024;   // flattened; mconv swizzles internally
    unsigned short* cur = act0;
    unsigned short* nxt = act1;
    auto swap = [&]() { unsigned short* t = cur; cur = nxt; nxt = t; };

    for (int i = 0; i < 3; ++i) {
        mconv<4, true, false, false, true, false>
            <<<grid, 256, 0, stream>>>(cur, wmod[i], nullptr, noise[i], m_wn[i], nxt);
        swap();
        mconv<4, false, true, true, false, false>
            <<<grid, 256, 0, stream>>>(cur, wfix[i], m_cb[i], nullptr, nullptr, nxt);
        swap();
        mconv<4, false, true, false, false, false>
            <<<grid, 256, 0, stream>>>(cur, wfix[3 + i], b_hr[i], nullptr, nullptr, nxt);
        swap();
    }
    mconv<4, false, true, false, false, false>
        <<<grid, 256, 0, stream>>>(cur, wfix[6], b_hr[3], nullptr, nullptr, nxt);
    swap();
    mconv<4, false, true, false, false, false>
        <<<grid, 256, 0, stream>>>(cur, wfix[7], b_hr[4], nullptr, nullptr, nxt);
    swap();
    mconv<1, false, true, false, false, true>
        <<<grid, 256, 0, stream>>>(cur, wlast, b_last, nullptr, nullptr, d_out);
}